// Round 5
// baseline (1957.202 us; speedup 1.0000x reference)
//
#include <hip/hip_runtime.h>

#define NV 50000
#define NE 5000
#define NC 16
#define TAU_INV 2.0f
#define EPS 1e-8f

#define NLANE 5120      // 5 x-blocks * 1024 edge slots
#define EBLK 1024       // edges per x-block (4 per lane * 256 threads)
#define NXB 5
#define NCH 100         // v-chunks
#define VCH 500         // NV / NCH
#define GRP 5           // h-load group (ring depth): 500 % 5 == 0

// ---------------- softmax: one thread per row, both pred_s and pred_t.
// Output layout: p[v][32] = [softmax(pred_s[v]) (16) | softmax(pred_t[v]) (16)]
__global__ __launch_bounds__(256) void softmax_kernel(
    const float* __restrict__ pred_s, const float* __restrict__ pred_t,
    float* __restrict__ p) {
  int i = blockIdx.x * 256 + threadIdx.x;
  if (i >= 2 * NV) return;
  const float* src;
  float* dst;
  if (i < NV) { src = pred_s + (size_t)i * NC; dst = p + (size_t)i * 32; }
  else        { int j = i - NV; src = pred_t + (size_t)j * NC; dst = p + (size_t)j * 32 + 16; }
  float4 a = ((const float4*)src)[0];
  float4 b = ((const float4*)src)[1];
  float4 c = ((const float4*)src)[2];
  float4 d = ((const float4*)src)[3];
  float x[16] = {a.x,a.y,a.z,a.w, b.x,b.y,b.z,b.w, c.x,c.y,c.z,c.w, d.x,d.y,d.z,d.w};
  float mx = x[0];
#pragma unroll
  for (int k = 1; k < 16; ++k) mx = fmaxf(mx, x[k]);
  float sum = 0.f;
#pragma unroll
  for (int k = 0; k < 16; ++k) { x[k] = expf(x[k] - mx); sum += x[k]; }
  float inv = 1.f / sum;
#pragma unroll
  for (int k = 0; k < 16; ++k) x[k] *= inv;
  float4 o0 = {x[0], x[1], x[2], x[3]};
  float4 o1 = {x[4], x[5], x[6], x[7]};
  float4 o2 = {x[8], x[9], x[10], x[11]};
  float4 o3 = {x[12], x[13], x[14], x[15]};
  ((float4*)dst)[0] = o0;
  ((float4*)dst)[1] = o1;
  ((float4*)dst)[2] = o2;
  ((float4*)dst)[3] = o3;
}

// ---------------- main accumulation.
// Key change vs R4: p slice lives in LDS (lgkmcnt domain), so the vmcnt FIFO
// carries ONLY the H stream -> h group-loads stay outstanding across the whole
// FMA block (1280 cyc >> 900 cyc HBM latency), no exposed latency.
// part layout (floats): part[y][k][NLANE], k: 0..15 = S, 16..31 = T, 32 = deg
__global__ __launch_bounds__(256, 2) void accum_kernel(
    const float* __restrict__ H, const float* __restrict__ p,
    float* __restrict__ part) {
  __shared__ float lp[VCH * 32];   // 64000 B
  int xb = blockIdx.x;
  int y  = blockIdx.y;
  int e0 = xb * EBLK + 4 * (int)threadIdx.x;
  if (e0 > NE - 4) e0 = NE - 4;   // dup lanes store identical values: benign
  int v0 = y * VCH;

  // stage the p slice (contiguous 64 KB) into LDS, coalesced float4
  {
    const float4* __restrict__ src = (const float4*)(p + (size_t)v0 * 32);
    float4* dst = (float4*)lp;
    for (int i = threadIdx.x; i < VCH * 8; i += 256) dst[i] = src[i];
  }
  __syncthreads();

  float4 aS[16], aT[16], dg;
#pragma unroll
  for (int k = 0; k < 16; ++k) {
    aS[k] = make_float4(0.f, 0.f, 0.f, 0.f);
    aT[k] = make_float4(0.f, 0.f, 0.f, 0.f);
  }
  dg = make_float4(0.f, 0.f, 0.f, 0.f);

  const float* __restrict__ hbase = H + (size_t)v0 * NE + e0;

  float4 hc[GRP];
#pragma unroll
  for (int u = 0; u < GRP; ++u)
    hc[u] = *(const float4*)(hbase + (size_t)u * NE);

  for (int vb = 0; vb < VCH; vb += GRP) {
    // prefetch next GRP rows (only h in the vmcnt queue now)
    int nb = (vb + GRP < VCH) ? vb + GRP : vb;
    float4 hn[GRP];
#pragma unroll
    for (int u = 0; u < GRP; ++u)
      hn[u] = *(const float4*)(hbase + (size_t)(nb + u) * NE);

#pragma unroll
    for (int u = 0; u < GRP; ++u) {
      const float4* __restrict__ r = (const float4*)(lp + (size_t)(vb + u) * 32);
      float4 s0 = r[0], s1 = r[1], s2 = r[2], s3 = r[3];
      float4 t0 = r[4], t1 = r[5], t2 = r[6], t3 = r[7];
      float4 h = hc[u];
      dg.x += h.x; dg.y += h.y; dg.z += h.z; dg.w += h.w;
      float sv[16] = {s0.x,s0.y,s0.z,s0.w, s1.x,s1.y,s1.z,s1.w,
                      s2.x,s2.y,s2.z,s2.w, s3.x,s3.y,s3.z,s3.w};
      float tv[16] = {t0.x,t0.y,t0.z,t0.w, t1.x,t1.y,t1.z,t1.w,
                      t2.x,t2.y,t2.z,t2.w, t3.x,t3.y,t3.z,t3.w};
#pragma unroll
      for (int k = 0; k < 16; ++k) {
        aS[k].x = fmaf(h.x, sv[k], aS[k].x);
        aS[k].y = fmaf(h.y, sv[k], aS[k].y);
        aS[k].z = fmaf(h.z, sv[k], aS[k].z);
        aS[k].w = fmaf(h.w, sv[k], aS[k].w);
        aT[k].x = fmaf(h.x, tv[k], aT[k].x);
        aT[k].y = fmaf(h.y, tv[k], aT[k].y);
        aT[k].z = fmaf(h.z, tv[k], aT[k].z);
        aT[k].w = fmaf(h.w, tv[k], aT[k].w);
      }
    }
#pragma unroll
    for (int u = 0; u < GRP; ++u) hc[u] = hn[u];
  }

  float* op = part + (size_t)y * 33 * NLANE + e0;
#pragma unroll
  for (int k = 0; k < 16; ++k)
    *(float4*)(op + (size_t)k * NLANE) = aS[k];
#pragma unroll
  for (int k = 0; k < 16; ++k)
    *(float4*)(op + (size_t)(16 + k) * NLANE) = aT[k];
  *(float4*)(op + (size_t)32 * NLANE) = dg;
}

// ---------------- reduce the NCH partials: acc[k][NLANE] = sum_y part[y][k][NLANE]
__global__ __launch_bounds__(256) void reduce_kernel(
    const float* __restrict__ part, float* __restrict__ acc) {
  int i = blockIdx.x * 256 + threadIdx.x;
  if (i >= 33 * NLANE) return;
  float s = 0.f;
#pragma unroll 4
  for (int y = 0; y < NCH; ++y) s += part[(size_t)y * 33 * NLANE + i];
  acc[i] = s;
}

// ---------------- per-edge KL + masked reduction (single block, 256 threads)
// acc layout: acc[k*NLANE + e]; S at k, T at 16+k, deg at 32
__global__ __launch_bounds__(256) void kl_kernel(
    const float* __restrict__ acc, const unsigned char* __restrict__ e_mask,
    float* __restrict__ out) {
  __shared__ float snum[4];
  __shared__ float scnt[4];
  int t = threadIdx.x;
  float num = 0.f, cnt = 0.f;
  for (int e = t; e < NE; e += 256) {
    if (e_mask[e]) {
      float deg = acc[(size_t)32 * NLANE + e];
      float invd = 1.f / deg;
      float kl = 0.f;
#pragma unroll
      for (int k = 0; k < 16; ++k) {
        float ms = acc[(size_t)k * NLANE + e] * invd;
        float mt = acc[(size_t)(16 + k) * NLANE + e] * invd;
        float xs = ms * TAU_INV + EPS;
        float xt = mt * TAU_INV + EPS;
        kl += xt * (logf(xt) - logf(xs));
      }
      num += kl;
      cnt += 1.f;
    }
  }
#pragma unroll
  for (int off = 32; off > 0; off >>= 1) {
    num += __shfl_down(num, off, 64);
    cnt += __shfl_down(cnt, off, 64);
  }
  if ((t & 63) == 0) { snum[t >> 6] = num; scnt[t >> 6] = cnt; }
  __syncthreads();
  if (t == 0) {
    float n = snum[0] + snum[1] + snum[2] + snum[3];
    float c2 = scnt[0] + scnt[1] + scnt[2] + scnt[3];
    out[0] = n / fmaxf(c2, 1.f);
  }
}

extern "C" void kernel_launch(void* const* d_in, const int* in_sizes, int n_in,
                              void* d_out, int out_size, void* d_ws, size_t ws_size,
                              hipStream_t stream) {
  const float* pred_s = (const float*)d_in[0];
  const float* pred_t = (const float*)d_in[1];
  const float* H      = (const float*)d_in[2];
  const unsigned char* e_mask = (const unsigned char*)d_in[3];

  float* ws   = (float*)d_ws;
  float* p    = ws;                                    // NV*32        (6.40 MB)
  float* acc  = ws + (size_t)NV * 32;                  // 33*NLANE     (0.68 MB)
  float* part = acc + (size_t)33 * NLANE;              // NCH*33*NLANE (67.6 MB)

  softmax_kernel<<<dim3((2 * NV + 255) / 256), 256, 0, stream>>>(pred_s, pred_t, p);
  accum_kernel<<<dim3(NXB, NCH), 256, 0, stream>>>(H, p, part);
  reduce_kernel<<<dim3((33 * NLANE + 255) / 256), 256, 0, stream>>>(part, acc);
  kl_kernel<<<1, 256, 0, stream>>>(acc, e_mask, (float*)d_out);
}

// Round 6
// 1416.083 us; speedup vs baseline: 1.3821x; 1.3821x over previous
//
#include <hip/hip_runtime.h>

#define NV 50000
#define NE 5000
#define NC 16
#define TAU_INV 2.0f
#define EPS 1e-8f

#define NCH 200         // v-chunks
#define VCH 250         // NV / NCH ; LDS slice = 250*32*4 = 31.25 KB
#define GRP 10          // h-load ring depth (250 % 10 == 0)
#define NXB 20          // x-blocks; 20*256 = 5120 edge slots >= 5000
#define NLANE 5120

// ---------------- softmax: one thread per row, both pred_s and pred_t.
// Output layout: p[v][32] = [softmax(pred_s[v]) (16) | softmax(pred_t[v]) (16)]
__global__ __launch_bounds__(256) void softmax_kernel(
    const float* __restrict__ pred_s, const float* __restrict__ pred_t,
    float* __restrict__ p) {
  int i = blockIdx.x * 256 + threadIdx.x;
  if (i >= 2 * NV) return;
  const float* src;
  float* dst;
  if (i < NV) { src = pred_s + (size_t)i * NC; dst = p + (size_t)i * 32; }
  else        { int j = i - NV; src = pred_t + (size_t)j * NC; dst = p + (size_t)j * 32 + 16; }
  float4 a = ((const float4*)src)[0];
  float4 b = ((const float4*)src)[1];
  float4 c = ((const float4*)src)[2];
  float4 d = ((const float4*)src)[3];
  float x[16] = {a.x,a.y,a.z,a.w, b.x,b.y,b.z,b.w, c.x,c.y,c.z,c.w, d.x,d.y,d.z,d.w};
  float mx = x[0];
#pragma unroll
  for (int k = 1; k < 16; ++k) mx = fmaxf(mx, x[k]);
  float sum = 0.f;
#pragma unroll
  for (int k = 0; k < 16; ++k) { x[k] = expf(x[k] - mx); sum += x[k]; }
  float inv = 1.f / sum;
#pragma unroll
  for (int k = 0; k < 16; ++k) x[k] *= inv;
  float4 o0 = {x[0], x[1], x[2], x[3]};
  float4 o1 = {x[4], x[5], x[6], x[7]};
  float4 o2 = {x[8], x[9], x[10], x[11]};
  float4 o3 = {x[12], x[13], x[14], x[15]};
  ((float4*)dst)[0] = o0;
  ((float4*)dst)[1] = o1;
  ((float4*)dst)[2] = o2;
  ((float4*)dst)[3] = o3;
}

// ---------------- main accumulation, 1 edge per lane (spill-free by design):
// per-lane state = 33 acc + GRP ring + temps ~= 100 VGPR. p slice in LDS
// (31.25 KB -> up to 5 blocks/CU); H ring keeps 2.5 KB/wave of HBM loads in
// flight with nothing else in the vmcnt queue.
// part layout (floats): part[y][k][NLANE], k: 0..15 = S, 16..31 = T, 32 = deg
__global__ __launch_bounds__(256) void accum_kernel(
    const float* __restrict__ H, const float* __restrict__ p,
    float* __restrict__ part) {
  __shared__ float lp[VCH * 32];   // 31.25 KB
  int xb = blockIdx.x;
  int y  = blockIdx.y;
  int e = xb * 256 + (int)threadIdx.x;
  if (e >= NE) e = NE - 1;        // dup lanes write identical values: benign
  int v0 = y * VCH;

  // stage the p slice (contiguous 32 KB) into LDS, coalesced float4
  {
    const float4* __restrict__ src = (const float4*)(p + (size_t)v0 * 32);
    float4* dst = (float4*)lp;
    for (int i = threadIdx.x; i < VCH * 8; i += 256) dst[i] = src[i];
  }
  __syncthreads();

  float aS[16], aT[16], dg = 0.f;
#pragma unroll
  for (int k = 0; k < 16; ++k) { aS[k] = 0.f; aT[k] = 0.f; }

  const float* __restrict__ hp = H + (size_t)v0 * NE + e;

  float hc[GRP];
#pragma unroll
  for (int u = 0; u < GRP; ++u) hc[u] = hp[(size_t)u * NE];

  for (int vb = 0; vb < VCH; vb += GRP) {
    int nb = (vb + GRP < VCH) ? vb + GRP : vb;   // last iter: benign re-load
    float hn[GRP];
#pragma unroll
    for (int u = 0; u < GRP; ++u) hn[u] = hp[(size_t)(nb + u) * NE];

#pragma unroll
    for (int u = 0; u < GRP; ++u) {
      const float4* __restrict__ r = (const float4*)(lp + (size_t)(vb + u) * 32);
      float4 s0 = r[0], s1 = r[1], s2 = r[2], s3 = r[3];
      float4 t0 = r[4], t1 = r[5], t2 = r[6], t3 = r[7];
      float h = hc[u];
      dg += h;
      float sv[16] = {s0.x,s0.y,s0.z,s0.w, s1.x,s1.y,s1.z,s1.w,
                      s2.x,s2.y,s2.z,s2.w, s3.x,s3.y,s3.z,s3.w};
      float tv[16] = {t0.x,t0.y,t0.z,t0.w, t1.x,t1.y,t1.z,t1.w,
                      t2.x,t2.y,t2.z,t2.w, t3.x,t3.y,t3.z,t3.w};
#pragma unroll
      for (int k = 0; k < 16; ++k) aS[k] = fmaf(h, sv[k], aS[k]);
#pragma unroll
      for (int k = 0; k < 16; ++k) aT[k] = fmaf(h, tv[k], aT[k]);
    }
#pragma unroll
    for (int u = 0; u < GRP; ++u) hc[u] = hn[u];
  }

  float* op = part + (size_t)y * 33 * NLANE + e;
#pragma unroll
  for (int k = 0; k < 16; ++k) op[(size_t)k * NLANE] = aS[k];
#pragma unroll
  for (int k = 0; k < 16; ++k) op[(size_t)(16 + k) * NLANE] = aT[k];
  op[(size_t)32 * NLANE] = dg;
}

// ---------------- reduce the NCH partials: acc[k][NLANE] = sum_y part[y][k][NLANE]
__global__ __launch_bounds__(256) void reduce_kernel(
    const float* __restrict__ part, float* __restrict__ acc) {
  int i = blockIdx.x * 256 + threadIdx.x;
  if (i >= 33 * NLANE) return;
  float s = 0.f;
#pragma unroll 4
  for (int y = 0; y < NCH; ++y) s += part[(size_t)y * 33 * NLANE + i];
  acc[i] = s;
}

// ---------------- per-edge KL + masked reduction (single block, 256 threads)
// acc layout: acc[k*NLANE + e]; S at k, T at 16+k, deg at 32
__global__ __launch_bounds__(256) void kl_kernel(
    const float* __restrict__ acc, const unsigned char* __restrict__ e_mask,
    float* __restrict__ out) {
  __shared__ float snum[4];
  __shared__ float scnt[4];
  int t = threadIdx.x;
  float num = 0.f, cnt = 0.f;
  for (int e = t; e < NE; e += 256) {
    if (e_mask[e]) {
      float deg = acc[(size_t)32 * NLANE + e];
      float invd = 1.f / deg;
      float kl = 0.f;
#pragma unroll
      for (int k = 0; k < 16; ++k) {
        float ms = acc[(size_t)k * NLANE + e] * invd;
        float mt = acc[(size_t)(16 + k) * NLANE + e] * invd;
        float xs = ms * TAU_INV + EPS;
        float xt = mt * TAU_INV + EPS;
        kl += xt * (logf(xt) - logf(xs));
      }
      num += kl;
      cnt += 1.f;
    }
  }
#pragma unroll
  for (int off = 32; off > 0; off >>= 1) {
    num += __shfl_down(num, off, 64);
    cnt += __shfl_down(cnt, off, 64);
  }
  if ((t & 63) == 0) { snum[t >> 6] = num; scnt[t >> 6] = cnt; }
  __syncthreads();
  if (t == 0) {
    float n = snum[0] + snum[1] + snum[2] + snum[3];
    float c2 = scnt[0] + scnt[1] + scnt[2] + scnt[3];
    out[0] = n / fmaxf(c2, 1.f);
  }
}

extern "C" void kernel_launch(void* const* d_in, const int* in_sizes, int n_in,
                              void* d_out, int out_size, void* d_ws, size_t ws_size,
                              hipStream_t stream) {
  const float* pred_s = (const float*)d_in[0];
  const float* pred_t = (const float*)d_in[1];
  const float* H      = (const float*)d_in[2];
  const unsigned char* e_mask = (const unsigned char*)d_in[3];

  float* ws   = (float*)d_ws;
  float* p    = ws;                                    // NV*32         (6.40 MB)
  float* acc  = ws + (size_t)NV * 32;                  // 33*NLANE      (0.68 MB)
  float* part = acc + (size_t)33 * NLANE;              // NCH*33*NLANE  (135 MB)

  softmax_kernel<<<dim3((2 * NV + 255) / 256), 256, 0, stream>>>(pred_s, pred_t, p);
  accum_kernel<<<dim3(NXB, NCH), 256, 0, stream>>>(H, p, part);
  reduce_kernel<<<dim3((33 * NLANE + 255) / 256), 256, 0, stream>>>(part, acc);
  kl_kernel<<<1, 256, 0, stream>>>(acc, e_mask, (float*)d_out);
}